// Round 11
// baseline (364.455 us; speedup 1.0000x reference)
//
#include <hip/hip_runtime.h>
#include <hip/hip_fp16.h>

#define N_NODES 100000
#define KK 5
#define CC 16
#define EE 3200000
#define NXCC 8

#define NB 16                // row buckets
#define ROWS_PB 6250         // N_NODES / NB
#define WCAP 384             // entries per (chunk,bucket) window (+3.7 sigma)
#define WPAD 385             // LDS staging stride
#define BPB 64               // accum blocks per bucket (16*64 = 1024 blocks, 4/CU)
#define CHUNK 5120           // edges per scatter chunk
#define NCHUNK 3125          // 3125 * 5120 = 16,000,000
#define BLK_PER_K 625        // EE / CHUNK
#define SGRID 256            // persistent scatter blocks (1/CU)
#define STHREADS 1024        // 16 waves/CU (R10: +19% vs 8 waves)

typedef unsigned int uint2v __attribute__((ext_vector_type(2)));

__device__ __forceinline__ int xcc_id() {
    int x;
    asm volatile("s_getreg_b32 %0, hwreg(HW_REG_XCC_ID)" : "=s"(x));
    return x & (NXCC - 1);
}

// Kernel 1: Zt[k*N + n] (fp32, fallback) and Zh[k*N + n] (fp16, scatter)
__global__ void compute_z_kernel(const float* __restrict__ X,
                                 const float* __restrict__ h,
                                 float* __restrict__ Zt,
                                 __half* __restrict__ Zh) {
    int n = blockIdx.x * blockDim.x + threadIdx.x;
    if (n >= N_NODES) return;
    const float4* Xr = (const float4*)(X + (size_t)n * CC);
    float4 x0 = Xr[0], x1 = Xr[1], x2 = Xr[2], x3 = Xr[3];
    float xv[CC] = {x0.x, x0.y, x0.z, x0.w, x1.x, x1.y, x1.z, x1.w,
                    x2.x, x2.y, x2.z, x2.w, x3.x, x3.y, x3.z, x3.w};
#pragma unroll
    for (int k = 0; k < KK; ++k) {
        float acc = 0.0f;
#pragma unroll
        for (int c = 0; c < CC; ++c) acc += xv[c] * h[c * KK + k];
        Zt[k * N_NODES + n] = acc;
        Zh[k * N_NODES + n] = __float2half_rn(acc);
    }
}

// Phase A (R11): R10 structure + two overlap fixes.
//  (1) input double-buffer: chunk w+1's 6 loads issue at loop top, consumed
//      next iteration -- compiler can't hoist loads past __syncthreads, so
//      every chunk previously began with a ~600cyc L3 stall x12.2 chunks.
//  (2) flattened flush: prefix-sum over lcnt, all 1024 lanes store flat
//      indices (4-step binary search for bucket) -- was 16 bucket-loops at
//      384/1024 lanes active.
template<int SN>
__global__ __launch_bounds__(STHREADS, 1)
void scatter_lds_kernel(const int* __restrict__ rows,
                        const int* __restrict__ cols,
                        const float* __restrict__ vals,
                        const __half* __restrict__ Zh,
                        unsigned int* __restrict__ binned,
                        int* __restrict__ counts,
                        float* __restrict__ spill) {
    extern __shared__ char dynlds[];
    __half*       zsl = (__half*)dynlds;                          // SN*2 B
    unsigned int* buf = (unsigned int*)(dynlds + (size_t)SN * 2); // NB*WPAD*4
    __shared__ int lcnt[NB];
    __shared__ int pfx[NB + 1];
    int tid = threadIdx.x;
    int bid = blockIdx.x;
    int w0 = (int)(((long long)NCHUNK * bid) / SGRID);
    int w1 = (int)(((long long)NCHUNK * (bid + 1)) / SGRID);

    // ---- prologue: inputs for chunk w0 ----
    int4 rA, cA; float4 vA; int rsA, csA; float fsA;
    {
        int cbase = w0 * CHUNK;
        rA  = *(const int4*)(rows + cbase + tid * 4);
        cA  = *(const int4*)(cols + cbase + tid * 4);
        vA  = *(const float4*)(vals + cbase + tid * 4);
        int e4 = cbase + 4096 + tid;
        rsA = rows[e4]; csA = cols[e4]; fsA = vals[e4];
    }

    int klast = -1;
    for (int w = w0; w < w1; ++w) {
        // ---- prefetch chunk w+1 inputs (overlap slice-copy/gather/flush) --
        int4 rB = {}, cB = {}; float4 vB = {};
        int rsB = 0, csB = 0; float fsB = 0.0f;
        if (w + 1 < w1) {
            int cb2 = (w + 1) * CHUNK;
            rB  = *(const int4*)(rows + cb2 + tid * 4);
            cB  = *(const int4*)(cols + cb2 + tid * 4);
            vB  = *(const float4*)(vals + cb2 + tid * 4);
            int e4 = cb2 + 4096 + tid;
            rsB = rows[e4]; csB = cols[e4]; fsB = vals[e4];
        }

        int k = w / BLK_PER_K;                             // block-uniform
        const __half* Zk_h = Zh + (size_t)k * N_NODES;
        if (SN > 0 && k != klast) {
            __syncthreads();                               // prior chunk done with zsl
            const float4* zsrc = (const float4*)Zk_h;      // 16B-aligned
            float4*       zdst = (float4*)dynlds;
#pragma unroll
            for (int i = 0; i < SN / 8192; ++i)            // SN/8 float4s, 1024 thr
                zdst[tid + i * 1024] = zsrc[tid + i * 1024];
            klast = k;
            __syncthreads();
        }
        if (tid < NB) lcnt[tid] = 0;
        __syncthreads();

        int   cix[5] = {cA.x, cA.y, cA.z, cA.w, csA};
        int   rr[5]  = {rA.x, rA.y, rA.z, rA.w, rsA};
        float vv[5]  = {vA.x, vA.y, vA.z, vA.w, fsA};

        // ---- gathers: LDS slice hit (~65%) or residual L2/L3 request ----
        float z[5];
#pragma unroll
        for (int i = 0; i < 5; ++i) {
            unsigned c = (unsigned)cix[i];
            __half hz;
            if (SN > 0 && c < (unsigned)SN) hz = zsl[c];
            else                            hz = Zk_h[c];
            z[i] = __half2float(hz);
        }

        // ---- LDS position allocation (overlaps residual gathers) ----
        int pos[5];
#pragma unroll
        for (int i = 0; i < 5; ++i) {
            int b = rr[i] / ROWS_PB;                       // magic-mul
            pos[i] = atomicAdd(&lcnt[b], 1);
        }

        // ---- pack + stage ----
#pragma unroll
        for (int i = 0; i < 5; ++i) {
            int b = rr[i] / ROWS_PB;
            float cb = vv[i] * z[i];
            int p = pos[i];
            if (p < WCAP) {
                unsigned int packed =
                    ((unsigned)(rr[i] - b * ROWS_PB) << 16) |
                    (unsigned)__half_as_ushort(__float2half_rn(cb));
                buf[b * WPAD + p] = packed;
            } else {
                unsafeAtomicAdd(&spill[rr[i]], cb);        // exact, ~never taken
            }
        }
        __syncthreads();

        // ---- flattened flush: prefix-sum + all-lane dense stores ----
        if (tid == 0) {
            int s = 0;
#pragma unroll
            for (int b = 0; b < NB; ++b) { pfx[b] = s; s += min(lcnt[b], WCAP); }
            pfx[NB] = s;
        }
        __syncthreads();
        int total = pfx[NB];                               // ~5120
        unsigned int* wbase = binned + (size_t)w * WCAP;
        for (int i = tid; i < total; i += STHREADS) {
            int b = 0;
#pragma unroll
            for (int j = 8; j >= 1; j >>= 1)
                if (pfx[b + j] <= i) b += j;
            int p = i - pfx[b];
            wbase[(size_t)b * ((size_t)NCHUNK * WCAP) + p] = buf[b * WPAD + p];
        }
        if (tid < NB) counts[w * NB + tid] = min(lcnt[tid], WCAP);
        __syncthreads();                                   // buf/lcnt/pfx reuse
        rA = rB; cA = cB; vA = vB; rsA = rsB; csA = csB; fsA = fsB;
    }
}

// Phase B (R10-verbatim, control): counts in LDS; uint2 payload, two windows
// concurrent (tid split 2x256), 16 windows/outer iter, 8 loads in flight.
__global__ __launch_bounds__(512, 2)
void accum_kernel(const unsigned int* __restrict__ binned,
                  const int* __restrict__ counts,
                  float* __restrict__ partials) {
    __shared__ float acc[ROWS_PB];                    // 25 KB
    __shared__ int cnts[56];                          // whi-wlo <= 49
    int b = blockIdx.x / BPB;
    int s = blockIdx.x % BPB;
    int tid = threadIdx.x;
    int wlo = (NCHUNK * s) / BPB;
    int whi = (NCHUNK * (s + 1)) / BPB;
    for (int i = tid; i < ROWS_PB; i += 512) acc[i] = 0.0f;
    if (tid < whi - wlo) cnts[tid] = counts[(wlo + tid) * NB + b];
    __syncthreads();

    const unsigned int* bbase = binned + (size_t)b * ((size_t)NCHUNK * WCAP);
    int t    = tid & 255;                             // entry-pair index
    int half = tid >> 8;                              // which window of the pair
    for (int w0 = wlo; w0 < whi; w0 += 16) {
        uint2v e[8];
        int ok0[8], ok1[8];
#pragma unroll
        for (int j = 0; j < 8; ++j) {
            int w = w0 + 2 * j + half;
            int cnt = (w < whi) ? cnts[w - wlo] : 0;
            ok0[j] = 2 * t < cnt;
            ok1[j] = 2 * t + 1 < cnt;
            const uint2v* src = (const uint2v*)(bbase + (size_t)w * WCAP);
            uint2v ez = {0u, 0u};
            e[j] = ok0[j] ? src[t] : ez;              // exec-masked 8B load
        }
#pragma unroll
        for (int j = 0; j < 8; ++j) {
            if (ok0[j])
                atomicAdd(&acc[e[j][0] >> 16],
                          __half2float(__ushort_as_half((unsigned short)(e[j][0] & 0xFFFFu))));
            if (ok1[j])
                atomicAdd(&acc[e[j][1] >> 16],
                          __half2float(__ushort_as_half((unsigned short)(e[j][1] & 0xFFFFu))));
        }
    }
    __syncthreads();
    float* dst = partials + (size_t)blockIdx.x * ROWS_PB;
    for (int i = tid; i < ROWS_PB; i += 512) dst[i] = acc[i];
}

// y[n] = spill[n] + sum over BPB partial slices of n's bucket
__global__ void reduce_kernel(const float* __restrict__ partials,
                              const float* __restrict__ spill,
                              float* __restrict__ y) {
    int n = blockIdx.x * blockDim.x + threadIdx.x;
    if (n >= N_NODES) return;
    int b = n / ROWS_PB, loc = n - b * ROWS_PB;
    const float* p = partials + (size_t)(b * BPB) * ROWS_PB + loc;
    float acc = spill[n];
#pragma unroll 8
    for (int s = 0; s < BPB; ++s) acc += p[(size_t)s * ROWS_PB];
    y[n] = acc;
}

// ---------- fallback path: far-atomic scatter, used if ws too small ----
__global__ void edge_kernel_atomic(const int* __restrict__ rows,
                                   const int* __restrict__ cols,
                                   const float* __restrict__ vals,
                                   const float* __restrict__ Zt,
                                   float* __restrict__ yrep) {
    int t = blockIdx.x * blockDim.x + threadIdx.x;
    int base = t * 4;
    if (base >= KK * EE) return;
    int k = base / EE;
    const float* Zk = Zt + (size_t)k * N_NODES;
    float* y = yrep + (size_t)xcc_id() * N_NODES;
    int4 r = *(const int4*)(rows + base);
    int4 c = *(const int4*)(cols + base);
    float4 v = *(const float4*)(vals + base);
    unsafeAtomicAdd(&y[r.x], v.x * Zk[c.x]);
    unsafeAtomicAdd(&y[r.y], v.y * Zk[c.y]);
    unsafeAtomicAdd(&y[r.z], v.z * Zk[c.z]);
    unsafeAtomicAdd(&y[r.w], v.w * Zk[c.w]);
}

__global__ void reduce8_kernel(const float* __restrict__ yrep, float* __restrict__ y) {
    int n = blockIdx.x * blockDim.x + threadIdx.x;
    if (n >= N_NODES) return;
    float acc = 0.0f;
#pragma unroll
    for (int r = 0; r < NXCC; ++r) acc += yrep[(size_t)r * N_NODES + n];
    y[n] = acc;
}

extern "C" void kernel_launch(void* const* d_in, const int* in_sizes, int n_in,
                              void* d_out, int out_size, void* d_ws, size_t ws_size,
                              hipStream_t stream) {
    const float* X    = (const float*)d_in[0];
    const int*   rows = (const int*)  d_in[1];
    const int*   cols = (const int*)  d_in[2];
    const float* vals = (const float*)d_in[3];
    const float* h    = (const float*)d_in[4];
    float* y = (float*)d_out;

    char* ws = (char*)d_ws;
    float*  Zt = (float*)ws;                                   //  2,000,000 B
    size_t zh_off      = 2000000;                              //  1,000,000 B
    size_t counts_off  = 3000000;                              //    200,000 B
    size_t spill_off   = 3200000;                              //    400,000 B
    size_t binned_off  = 3600000;
    size_t binned_sz   = (size_t)NCHUNK * NB * WCAP * 4;       //  76,800,000 B
    size_t partial_off = binned_off + binned_sz;
    size_t partial_sz  = (size_t)NB * BPB * ROWS_PB * 4;       //  25,600,000 B
    size_t need = partial_off + partial_sz;                    // ~106.0 MB
    __half* Zh = (__half*)(ws + zh_off);

    {   // Z = X @ h  (Zt layout [k][n], fp32 + fp16)
        int threads = 256;
        int blocks  = (N_NODES + threads - 1) / threads;
        compute_z_kernel<<<blocks, threads, 0, stream>>>(X, h, Zt, Zh);
    }

    if (ws_size >= need) {
        int*          counts   = (int*)(ws + counts_off);
        float*        spill    = (float*)(ws + spill_off);
        unsigned int* binned   = (unsigned int*)(ws + binned_off);
        float*        partials = (float*)(ws + partial_off);
        hipMemsetAsync(spill, 0, 400000, stream);

        // runtime probe: largest launchable Z-slice (capture-legal queries only)
        static int g_sn = -1;
        const size_t stag = (size_t)NB * WPAD * 4;             // 24,640 B
        if (g_sn < 0) {
            g_sn = 0;
            int nb = 0;
            hipFuncSetAttribute((const void*)scatter_lds_kernel<65536>,
                                hipFuncAttributeMaxDynamicSharedMemorySize,
                                (int)(65536 * 2 + stag));
            if (hipOccupancyMaxActiveBlocksPerMultiprocessor(
                    &nb, scatter_lds_kernel<65536>, STHREADS, 65536 * 2 + stag) == hipSuccess
                && nb >= 1) g_sn = 65536;
            if (g_sn == 0) {
                nb = 0;
                hipFuncSetAttribute((const void*)scatter_lds_kernel<49152>,
                                    hipFuncAttributeMaxDynamicSharedMemorySize,
                                    (int)(49152 * 2 + stag));
                if (hipOccupancyMaxActiveBlocksPerMultiprocessor(
                        &nb, scatter_lds_kernel<49152>, STHREADS, 49152 * 2 + stag) == hipSuccess
                    && nb >= 1) g_sn = 49152;
            }
            if (g_sn == 0) {
                nb = 0;
                hipFuncSetAttribute((const void*)scatter_lds_kernel<32768>,
                                    hipFuncAttributeMaxDynamicSharedMemorySize,
                                    (int)(32768 * 2 + stag));
                if (hipOccupancyMaxActiveBlocksPerMultiprocessor(
                        &nb, scatter_lds_kernel<32768>, STHREADS, 32768 * 2 + stag) == hipSuccess
                    && nb >= 1) g_sn = 32768;
            }
        }
        size_t dyn = (size_t)g_sn * 2 + stag;
        switch (g_sn) {
        case 65536:
            scatter_lds_kernel<65536><<<SGRID, STHREADS, dyn, stream>>>(
                rows, cols, vals, Zh, binned, counts, spill);
            break;
        case 49152:
            scatter_lds_kernel<49152><<<SGRID, STHREADS, dyn, stream>>>(
                rows, cols, vals, Zh, binned, counts, spill);
            break;
        case 32768:
            scatter_lds_kernel<32768><<<SGRID, STHREADS, dyn, stream>>>(
                rows, cols, vals, Zh, binned, counts, spill);
            break;
        default:
            scatter_lds_kernel<0><<<SGRID, STHREADS, dyn, stream>>>(
                rows, cols, vals, Zh, binned, counts, spill);
            break;
        }

        accum_kernel<<<NB * BPB, 512, 0, stream>>>(binned, counts, partials);
        {
            int threads = 256;
            int blocks  = (N_NODES + threads - 1) / threads;
            reduce_kernel<<<blocks, threads, 0, stream>>>(partials, spill, y);
        }
    } else {
        // fallback: far-atomic path
        float* yrep = (float*)(ws + spill_off);
        hipMemsetAsync(yrep, 0, (size_t)NXCC * N_NODES * sizeof(float), stream);
        {
            int threads = 256;
            int blocks = ((KK * EE) / 4 + threads - 1) / threads;
            edge_kernel_atomic<<<blocks, threads, 0, stream>>>(rows, cols, vals, Zt, yrep);
        }
        {
            int threads = 256;
            int blocks  = (N_NODES + threads - 1) / threads;
            reduce8_kernel<<<blocks, threads, 0, stream>>>(yrep, y);
        }
    }
}